// Round 10
// baseline (133.361 us; speedup 1.0000x reference)
//
#include <hip/hip_runtime.h>
#include <hip/hip_bf16.h>
#include <math.h>

// MultiVariateAttention: out[b,u] = exp(mvn_logpdf(x[b]; mu[u], diag(s[u])))
// B = U = 4096, D = 16, fp32 in/out.
//
// R10: SINGLE kernel, producer/consumer (removes the pre-node + graph
// boundary, ~8-10us per the R4/R6/R8 decomposition ledger):
//  - blocks 0..31 compact params for 128 u's each into P (d_ws), then
//    __threadfence + agent-scope release flag. Distributed gather = same
//    cost as the standalone pre kernel (~1-2us), NOT the 64x-inflated
//    per-block re-gather that killed fused R4/R8.
//  - all 1024 blocks (<= 2048 co-residency bound at 4 waves/block ->
//    producers guaranteed resident) acquire-poll their slice's 4 flags,
//    s_sleep-throttled, bounded; on timeout fall back to inline params
//    (correct, never deadlocks). Replays: flags already MAGIC -> skip,
//    P rewritten with identical values (benign).
//  - then the R9 body: x from LDS (no vmcnt waits in b-loop; stores
//    stream), v_pk_fma_f32 packed math, float2 stores.

#define TPB 256
#define DD 16
#define UPT 2        // u's per thread
#define BPB 32       // b rows per block; grid = 128*8 = 1024 blocks
#define NSLICE 8     // u-slices (also XCD-friendly: uslice = bid & 7)
#define NPROD 32     // producer blocks
#define UPP 128      // u's per producer = U/NPROD
#define FSTRIDE 16   // flag padding in uints (64B apart)
#define MAGIC 0x5CA1AB1Eu

typedef float v2f __attribute__((ext_vector_type(2)));

static constexpr float L2E   = 1.4426950408889634f;   // log2(e)
static constexpr float HL2PI = 0.91893853320467274f;  // 0.5*ln(2*pi)

// P layout: [2*D+1][U]. rows 0..15 = A1[d], 16..31 = A2[d], 32 = bias.
template <bool HAVE_WS>
__global__ __launch_bounds__(TPB, 4) void mva_one(
    const float* __restrict__ x,      // [B,1,D]
    const float* __restrict__ units,  // [U,D]
    const float* __restrict__ attn,   // [U,D,D]
    float* __restrict__ out,          // [B,U]
    float* __restrict__ P,
    unsigned int* __restrict__ flags,
    int U)
{
    const int bid    = blockIdx.x;
    const int uslice = bid & (NSLICE - 1);
    const int bchunk = bid >> 3;
    const int u0 = uslice * (TPB * UPT) + threadIdx.x * UPT;
    const int b0 = bchunk * BPB;

    __shared__ float xs[BPB][DD];
    __shared__ int tmo;
    {
        int i0 = threadIdx.x, i1 = threadIdx.x + TPB;
        float v0 = x[(size_t)b0 * DD + i0];
        float v1 = x[(size_t)b0 * DD + i1];
        xs[i0 >> 4][i0 & 15] = v0;
        xs[i1 >> 4][i1 & 15] = v1;
    }
    if (threadIdx.x == 0) tmo = HAVE_WS ? 0 : 1;

    // ---- producer phase: compact params for this block's 128 u's ----
    if (HAVE_WS && bid < NPROD) {
        const int ub = bid * UPP;
#pragma unroll
        for (int j = 0; j < (UPP * DD) / TPB; ++j) {   // 8 iters
            int q = j * TPB + threadIdx.x;
            int u = ub + (q >> 4), d = q & 15;
            float s  = fmaxf(attn[(size_t)u * DD * DD + d * (DD + 1)], 1e-6f);
            float w  = 1.f / (s * s);
            float mu = units[u * DD + d];
            P[(size_t)d * U + u]        = L2E * mu * w;
            P[(size_t)(DD + d) * U + u] = -0.5f * L2E * w;
            float bn = -0.5f * mu * mu * w - logf(s);
            bn += __shfl_xor(bn, 1, 16);
            bn += __shfl_xor(bn, 2, 16);
            bn += __shfl_xor(bn, 4, 16);
            bn += __shfl_xor(bn, 8, 16);
            if (d == 0) P[(size_t)(2 * DD) * U + u] = L2E * (bn - DD * HL2PI);
        }
        __syncthreads();  // block-uniform condition: legal
        if (threadIdx.x == 0) {
            __threadfence();  // device-scope: P visible before flag
            __hip_atomic_store(&flags[bid * FSTRIDE], MAGIC,
                               __ATOMIC_RELEASE, __HIP_MEMORY_SCOPE_AGENT);
        }
    }

    __syncthreads();  // tmo init + xs ordering before poll/use

    // ---- wait for the 4 producers covering this u-slice ----
    if (HAVE_WS && threadIdx.x < (TPB * UPT) / UPP) {  // lanes 0..3
        const unsigned int* f =
            &flags[(uslice * 4 + (int)threadIdx.x) * FSTRIDE];
        int it = 0;
        while (__hip_atomic_load(f, __ATOMIC_ACQUIRE,
                                 __HIP_MEMORY_SCOPE_AGENT) != MAGIC) {
            __builtin_amdgcn_s_sleep(2);
            if (++it > (1 << 18)) { tmo = 1; break; }  // never in practice
        }
    }
    __syncthreads();
    const bool use_p = HAVE_WS && (tmo == 0);  // block-uniform

    // ---- params: packed v2f ----
    v2f a1p[DD], a2p[DD], biasp;
    if (use_p) {
#pragma unroll
        for (int d = 0; d < DD; ++d) {
            a1p[d] = *reinterpret_cast<const v2f*>(P + (size_t)d * U + u0);
            a2p[d] = *reinterpret_cast<const v2f*>(P + (size_t)(DD + d) * U + u0);
        }
        biasp = *reinterpret_cast<const v2f*>(P + (size_t)(2 * DD) * U + u0);
    } else {
#pragma unroll
        for (int i = 0; i < UPT; ++i) {
            int u = u0 + i;
            float bn = 0.f;
#pragma unroll
            for (int d = 0; d < DD; ++d) {
                float s  = fmaxf(attn[(size_t)u * DD * DD + d * (DD + 1)], 1e-6f);
                float w  = 1.f / (s * s);
                float mu = units[u * DD + d];
                a1p[d][i] = L2E * mu * w;
                a2p[d][i] = -0.5f * L2E * w;
                bn += -0.5f * mu * mu * w - logf(s);
            }
            biasp[i] = L2E * (bn - DD * HL2PI);
        }
    }

    // ---- main loop: x from LDS broadcast; stores stream un-awaited ----
#pragma unroll 2
    for (int b = 0; b < BPB; ++b) {
        v2f acc = biasp;
#pragma unroll
        for (int j = 0; j < 4; ++j) {
            float4 xv = *reinterpret_cast<const float4*>(&xs[b][4 * j]);
            const int d = 4 * j;
            v2f xx, t;
            xx = (v2f){xv.x, xv.x};
            t   = __builtin_elementwise_fma(xx, a2p[d + 0], a1p[d + 0]);
            acc = __builtin_elementwise_fma(xx, t, acc);
            xx = (v2f){xv.y, xv.y};
            t   = __builtin_elementwise_fma(xx, a2p[d + 1], a1p[d + 1]);
            acc = __builtin_elementwise_fma(xx, t, acc);
            xx = (v2f){xv.z, xv.z};
            t   = __builtin_elementwise_fma(xx, a2p[d + 2], a1p[d + 2]);
            acc = __builtin_elementwise_fma(xx, t, acc);
            xx = (v2f){xv.w, xv.w};
            t   = __builtin_elementwise_fma(xx, a2p[d + 3], a1p[d + 3]);
            acc = __builtin_elementwise_fma(xx, t, acc);
        }
        float2 o;
        o.x = __builtin_amdgcn_exp2f(acc[0]);
        o.y = __builtin_amdgcn_exp2f(acc[1]);
        *reinterpret_cast<float2*>(out + (size_t)(b0 + b) * U + u0) = o;
    }
}

extern "C" void kernel_launch(void* const* d_in, const int* in_sizes, int n_in,
                              void* d_out, int out_size, void* d_ws, size_t ws_size,
                              hipStream_t stream) {
    const float* x     = (const float*)d_in[0];  // [B,1,D]
    const float* units = (const float*)d_in[1];  // [U,D]
    const float* attn  = (const float*)d_in[2];  // [U,D,D]
    float* out = (float*)d_out;

    const int B = in_sizes[0] / DD;  // 4096
    const int U = in_sizes[1] / DD;  // 4096

    const int nblk = (B / BPB) * NSLICE;  // 128 * 8 = 1024
    const size_t pbytes = (size_t)(2 * DD + 1) * U * sizeof(float);
    const size_t need   = pbytes + (size_t)NPROD * FSTRIDE * sizeof(unsigned);

    if (ws_size >= need) {
        float* P = (float*)d_ws;
        unsigned int* flags = (unsigned int*)((char*)d_ws + pbytes);
        mva_one<true><<<nblk, TPB, 0, stream>>>(x, units, attn, out, P, flags, U);
    } else {
        mva_one<false><<<nblk, TPB, 0, stream>>>(x, units, attn, out,
                                                 nullptr, nullptr, U);
    }
}

// Round 11
// 22.509 us; speedup vs baseline: 5.9247x; 5.9247x over previous
//
#include <hip/hip_runtime.h>
#include <hip/hip_bf16.h>
#include <math.h>

// MultiVariateAttention: out[b,u] = exp(mvn_logpdf(x[b]; mu[u], diag(s[u])))
// B = U = 4096, D = 16, fp32 in/out.
//
// R11: single fused kernel, tile = 32 u x 512 b (kills BOTH failure modes):
//  - R8's fused death was param re-gather L2 traffic: (B/Bb)*4.5MB.
//    Bb=32 -> 576MB (~45us). Bb=512 -> 36MB (~1us). Params shared via LDS.
//  - R10's death was cross-block spin-sync; here there is NO cross-block
//    anything: each block computes its own 32 u's params (2 scattered
//    loads/thread), no workspace, no flags, trivially replay-safe.
//  - no pre-kernel, no graph boundary (the ~8-10us bucket from R6 ledger).
//  - consumer loop = R9's proven body: x broadcast from LDS (lgkmcnt only
//    -> output stores are never awaited in-loop), v_pk_fma_f32 packed math.
//  - blockIdx.x = u-chunk: all 8 b-chunk blocks of a u-chunk hit the same
//    XCD's L2 for its attn panel (bid % 8 == uc % 8).

#define TPB 256
#define DD  16
#define UB  32     // u's per block
#define BB  512    // b's per block; grid (128, 8) = 1024 blocks = 4/CU

typedef float v2f __attribute__((ext_vector_type(2)));

static constexpr float L2E   = 1.4426950408889634f;   // log2(e)
static constexpr float HL2PI = 0.91893853320467274f;  // 0.5*ln(2*pi)

__global__ __launch_bounds__(TPB, 4) void mva_tile(
    const float* __restrict__ x,      // [B,1,D]
    const float* __restrict__ units,  // [U,D]
    const float* __restrict__ attn,   // [U,D,D]
    float* __restrict__ out,          // [B,U]
    int U)
{
    const int tid    = threadIdx.x;
    const int u_base = blockIdx.x * UB;
    const int b_base = blockIdx.y * BB;

    __shared__ float xs[BB][DD];          // 32 KB
    __shared__ float a1L[DD][UB + 2];     // +2 pad: float2-aligned, low conflict
    __shared__ float a2L[DD][UB + 2];
    __shared__ float biasL[UB];

    // ---- stage x tile (coalesced float4, 8 per thread) ----
    const float* xb = x + (size_t)b_base * DD;
#pragma unroll
    for (int r = 0; r < (BB * DD) / (TPB * 4); ++r) {  // 8 iters
        const int q = (r * TPB + tid) * 4;
        *reinterpret_cast<float4*>(&xs[0][0] + q) =
            *reinterpret_cast<const float4*>(xb + q);
    }

    // ---- param gather: 512 (u,d)-pairs over 256 threads (2 d's each) ----
    {
        const int ul = tid >> 3;          // 0..31  local u
        const int d0 = (tid & 7) * 2;     // 0,2,..,14
        const int u  = u_base + ul;
        float2 m = *reinterpret_cast<const float2*>(units + (size_t)u * DD + d0);
        const float* ar = attn + (size_t)u * DD * DD;
        float s0 = fmaxf(ar[d0 * (DD + 1)], 1e-6f);
        float s1 = fmaxf(ar[(d0 + 1) * (DD + 1)], 1e-6f);
        float w0 = 1.f / (s0 * s0);
        float w1 = 1.f / (s1 * s1);
        a1L[d0][ul]     = L2E * m.x * w0;
        a2L[d0][ul]     = -0.5f * L2E * w0;
        a1L[d0 + 1][ul] = L2E * m.y * w1;
        a2L[d0 + 1][ul] = -0.5f * L2E * w1;
        float bn = -0.5f * (m.x * m.x * w0 + m.y * m.y * w1)
                 - (logf(s0) + logf(s1));
        bn += __shfl_xor(bn, 1, 8);
        bn += __shfl_xor(bn, 2, 8);
        bn += __shfl_xor(bn, 4, 8);
        if ((tid & 7) == 0) biasL[ul] = L2E * (bn - DD * HL2PI);
    }
    __syncthreads();

    // ---- pull this thread's u-pair params into registers (packed) ----
    const int up = tid & 15;              // u-pair index: u = u_base + up*2
    const int br = tid >> 4;              // b-row offset 0..15
    v2f a1p[DD], a2p[DD];
#pragma unroll
    for (int d = 0; d < DD; ++d) {
        a1p[d] = *reinterpret_cast<const v2f*>(&a1L[d][up * 2]);
        a2p[d] = *reinterpret_cast<const v2f*>(&a2L[d][up * 2]);
    }
    const v2f biasp = *reinterpret_cast<const v2f*>(&biasL[up * 2]);

    // ---- main loop: 32 iters x 16 concurrent b-rows; stores stream ----
    float* orow = out + (size_t)b_base * U + u_base + up * 2;
#pragma unroll 2
    for (int it = 0; it < BB / 16; ++it) {
        const int b = it * 16 + br;
        v2f acc = biasp;
#pragma unroll
        for (int j = 0; j < 4; ++j) {
            // 16-lane groups share one address -> LDS broadcast; rows 2-way max.
            float4 xv = *reinterpret_cast<const float4*>(&xs[b][4 * j]);
            const int d = 4 * j;
            v2f xx, t;
            xx = (v2f){xv.x, xv.x};
            t   = __builtin_elementwise_fma(xx, a2p[d + 0], a1p[d + 0]);
            acc = __builtin_elementwise_fma(xx, t, acc);
            xx = (v2f){xv.y, xv.y};
            t   = __builtin_elementwise_fma(xx, a2p[d + 1], a1p[d + 1]);
            acc = __builtin_elementwise_fma(xx, t, acc);
            xx = (v2f){xv.z, xv.z};
            t   = __builtin_elementwise_fma(xx, a2p[d + 2], a1p[d + 2]);
            acc = __builtin_elementwise_fma(xx, t, acc);
            xx = (v2f){xv.w, xv.w};
            t   = __builtin_elementwise_fma(xx, a2p[d + 3], a1p[d + 3]);
            acc = __builtin_elementwise_fma(xx, t, acc);
        }
        float2 o;
        o.x = __builtin_amdgcn_exp2f(acc[0]);
        o.y = __builtin_amdgcn_exp2f(acc[1]);
        *reinterpret_cast<float2*>(orow + (size_t)b * U) = o;
    }
}

extern "C" void kernel_launch(void* const* d_in, const int* in_sizes, int n_in,
                              void* d_out, int out_size, void* d_ws, size_t ws_size,
                              hipStream_t stream) {
    const float* x     = (const float*)d_in[0];  // [B,1,D]
    const float* units = (const float*)d_in[1];  // [U,D]
    const float* attn  = (const float*)d_in[2];  // [U,D,D]
    float* out = (float*)d_out;

    const int B = in_sizes[0] / DD;  // 4096
    const int U = in_sizes[1] / DD;  // 4096

    dim3 grid(U / UB, B / BB);       // (128, 8) = 1024 blocks
    mva_tile<<<grid, TPB, 0, stream>>>(x, units, attn, out, U);
}